// Round 15
// baseline (165.416 us; speedup 1.0000x reference)
//
#include <hip/hip_runtime.h>
#include <math.h>

// Problem constants (fixed by reference setup_inputs): pred [32,1,512,512] f32
#define IMG_W 512
#define IMG_H 512
#define HW (IMG_W * IMG_H)      // 262144 = 2^18
#define LOGHW 18
#define NIMG 32
#define NTOT (NIMG * HW)        // 8388608
#define TILE 64
#define TPI 64                  // 8x8 tiles of 64x64 per image
#define NTILE (NIMG * TPI)      // 2048
#define CPI 64                  // stat-chunks per image (4096 px each)
#define NSCHUNK (NIMG * CPI)    // 2048
#define EDGE_N (NTILE * 64)     // 131072 entries per edge direction
#define NPAIR (NIMG * 112)      // 56 vertical + 56 horizontal tile-pairs/img
// NOTE (R6): no WIDE cross-kernel counter handshakes (2048-way on one address
// = 56us dead). 32-way and per-image 64-way (32 parallel addresses) are fine.
// NOTE (R12): no big register prefetch — VGPR 16->44 halved occupancy, +11us.
// NOTE (R8..R14): four structurally different k_local CCLs all land 120-121us
// total; k_local latency floor ~42us; harness fixed cost ~55us in-window.

// ---------------- lock-free min-index union-find ----------------------------
__device__ __forceinline__ void uf_unite(int* L, int a, int b) {
    while (true) {
        int p = ((volatile int*)L)[a];
        while (p != a) { a = p; p = ((volatile int*)L)[a]; }
        p = ((volatile int*)L)[b];
        while (p != b) { b = p; p = ((volatile int*)L)[b]; }
        if (a == b) return;
        if (a < b) { int t = a; a = b; b = t; }  // a > b
        int old = atomicMin(&L[a], b);
        if (old == a) return;
        a = old;
    }
}

// ---------------- K1: CCL + base BCE + edge export (R8 verbatim: best) ------
__global__ __launch_bounds__(512) void k_local(const float* __restrict__ pred,
                                               int* __restrict__ L,
                                               float* __restrict__ partials,
                                               int* __restrict__ edges,
                                               unsigned int* __restrict__ counters) {
    __shared__ int lab[TILE * TILE];   // 16 KB
    __shared__ float sred[512];        // 2 KB
    int tile = blockIdx.x;
    int img = tile >> 6;
    int t = tile & (TPI - 1);
    int ty = t >> 3, tx = t & 7;
    int baseLocal = (ty * TILE) * IMG_W + tx * TILE;  // image-local origin
    const float* pi = pred + ((size_t)img << LOGHW);
    int* Li = L + ((size_t)img << LOGHW);
    int tid = threadIdx.x;
    int lane = tid & 63, wave = tid >> 6;             // wave 0..7

    float acc = 0.0f;
    // ---- pass 1: row-run labels via ballot (wave w handles rows r%8==w) ----
#pragma unroll
    for (int j = 0; j < 8; j++) {
        int row = wave + j * 8;
        float p = pi[baseLocal + row * IMG_W + lane];
        acc += fmaxf(__logf(1.0f - p), -100.0f);   // 1-p exact for p>=0.5
        bool fg = (p >= 0.5f);
        unsigned long long bal = __ballot(fg);
        unsigned long long starts = bal & ~(bal << 1);
        unsigned long long maskle =
            (lane == 63) ? ~0ULL : ((1ULL << (lane + 1)) - 1ULL);
        int lb = -1;
        if (fg) {
            unsigned long long pre = starts & maskle;   // nonzero when fg
            lb = row * TILE + (63 - __builtin_clzll(pre));
        }
        lab[row * TILE + lane] = lb;
    }
    __syncthreads();
    // ---- pass 2: vertical unites, one per contact-run ----------------------
#pragma unroll
    for (int j = 0; j < 8; j++) {
        int row = wave + j * 8;
        if (row == 0) continue;                   // wave-uniform
        int i = row * TILE + lane;
        bool c = (lab[i] >= 0) && (lab[i - TILE] >= 0);
        unsigned long long cb = __ballot(c);
        unsigned long long cs = cb & ~(cb << 1);  // first lane of each contact
        if ((cs >> lane) & 1ULL) uf_unite(lab, i, i - TILE);
    }
    __syncthreads();
    // ---- pass 3a: run-starts chase to root (path halving + full compress) --
#pragma unroll
    for (int j = 0; j < 8; j++) {
        int row = wave + j * 8;
        int i = row * TILE + lane;
        bool fg = (lab[i] >= 0);
        unsigned long long bal = __ballot(fg);
        unsigned long long st = bal & ~(bal << 1);
        if ((st >> lane) & 1ULL) {
            int x = i, p = lab[x];
            while (p != x) {
                int g = lab[p];
                lab[x] = g;          // halving: benign race, ancestors only
                x = g;
                p = lab[x];
            }
            lab[i] = x;              // full compress for the start entry
        }
    }
    __syncthreads();
    // ---- pass 3b: gather roots (2 LDS reads/px) + global write (int4) ------
#pragma unroll
    for (int j = 0; j < 2; j++) {
        int i4 = (tid + j * 512) * 4;
        int ly = i4 >> 6, lx = i4 & 63;
        int4 o;
        int* op = (int*)&o;
#pragma unroll
        for (int k = 0; k < 4; k++) {
            int s = lab[i4 + k];                 // runstart (or root if start)
            if (s < 0) op[k] = -1;
            else {
                int r = lab[s];                  // root (starts compressed)
                op[k] = baseLocal + (r >> 6) * IMG_W + (r & 63);
            }
        }
        *(int4*)(Li + baseLocal + ly * IMG_W + lx) = o;
    }
    // ---- edge export: 4 x 64 labels, coalesced -----------------------------
    if (tid < 256) {
        int e = tid >> 6;                        // 0=T,1=B,2=L,3=R
        int q = tid & 63;
        int px = (e == 0) ? q
               : (e == 1) ? (63 * TILE + q)
               : (e == 2) ? (q * TILE)
               :            (q * TILE + 63);
        int s = lab[px];
        int val = -1;
        if (s >= 0) {
            int r = lab[s];
            val = baseLocal + (r >> 6) * IMG_W + (r & 63);
        }
        edges[e * EDGE_N + tile * 64 + q] = val;
    }
    // ---- base BCE block reduce ---------------------------------------------
    sred[tid] = acc;
    __syncthreads();
    for (int s = 256; s > 0; s >>= 1) {
        if (tid < s) sred[tid] += sred[tid + s];
        __syncthreads();
    }
    if (tid == 0) partials[blockIdx.x] = sred[0];
    if (blockIdx.x == 0 && tid <= NIMG) counters[tid] = 0u;  // 0xAA-poisoned
}

// ---------------- K2: cross-tile border unites from compact edges -----------
__global__ __launch_bounds__(256) void k_border(const int* __restrict__ edges,
                                                int* __restrict__ L) {
    int gid = blockIdx.x * blockDim.x + threadIdx.x;
    int pair = gid >> 6;                 // wave-uniform
    int lane = gid & 63;
    int a, b, img;
    if (pair < NIMG * 56) {              // vertical: (ty,tx)-(ty,tx+1)
        img = pair / 56;
        int w = pair - img * 56;
        int ty = w / 7, tx = w - ty * 7;
        int tl = img * TPI + ty * 8 + tx;
        a = edges[3 * EDGE_N + tl * 64 + lane];        // right edge of left
        b = edges[2 * EDGE_N + (tl + 1) * 64 + lane];  // left edge of right
    } else {                             // horizontal: (ty,tx)-(ty+1,tx)
        int p2 = pair - NIMG * 56;
        img = p2 / 56;
        int w = p2 - img * 56;
        int ty = w >> 3, tx = w & 7;
        int tu = img * TPI + ty * 8 + tx;
        a = edges[1 * EDGE_N + tu * 64 + lane];        // bottom edge of upper
        b = edges[0 * EDGE_N + (tu + 8) * 64 + lane];  // top edge of lower
    }
    bool c = (a >= 0) && (b >= 0);
    unsigned long long cb = __ballot(c);
    unsigned long long cs = cb & ~(cb << 1);           // contact-run starts
    if ((cs >> lane) & 1ULL)
        uf_unite(L + ((size_t)img << LOGHW), a, b);
}

// ---------------- K3: fused stats + rv + correction + final reduce ----------
// Stats phase (all 2048 blocks): per-chunk root count / max root / min fg via
// wave shfl reduces (2 barriers, not 8). Relaxed agent stores + per-image
// 64-way acq_rel counter elect the image's last finisher, which computes
// v = argmax(lf[1:]) + 1 (= last root index, with the root-at-0 / empty edge
// cases) and selects the v-th root -> rv; if rv >= 0 (rare) it scans its
// image for the correction sum_{root==rv}(logp - log1mp). A 32-way global
// counter elects the final reducer of 2048 base partials + 32 corrections.
__global__ __launch_bounds__(256) void k_stats_tail(
        const int* __restrict__ L, const float* __restrict__ pred,
        int* __restrict__ cntArr, int* __restrict__ maxArr,
        int* __restrict__ minArr, const float* __restrict__ partials,
        float* __restrict__ corr, unsigned int* __restrict__ counters,
        float* __restrict__ out) {
    __shared__ int sc[256], sm[256], sn[256];
    __shared__ int swc[4], swx[4], swn[4];
    __shared__ int sel_chunk, sel_base, result;
    __shared__ float sf[256];
    __shared__ double sd[256];
    __shared__ unsigned int oldc, oldg;
    int chunk = blockIdx.x;
    int img = chunk >> 6;
    int baseL = (chunk & 63) * 4096;             // image-local
    const int* Li = L + ((size_t)img << LOGHW);
    int t = threadIdx.x;
    int lane = t & 63, wv = t >> 6;
    // ---- stats over this chunk ---------------------------------------------
    int cnt = 0, mx = -1, mn = HW;
#pragma unroll
    for (int j = 0; j < 4; j++) {
        int off = baseL + (t + j * 256) * 4;
        int4 l4 = *(const int4*)(Li + off);
        const int* lp = (const int*)&l4;
#pragma unroll
        for (int k = 0; k < 4; k++) {
            int local = off + k;
            int p = lp[k];
            bool root = (p == local);
            cnt += root ? 1 : 0;
            if (root && local > mx) mx = local;
            if (p >= 0 && local >= 1 && local < mn) mn = local;
        }
    }
#pragma unroll
    for (int off = 32; off > 0; off >>= 1) {
        cnt += __shfl_down(cnt, off, 64);
        mx = max(mx, __shfl_down(mx, off, 64));
        mn = min(mn, __shfl_down(mn, off, 64));
    }
    if (lane == 0) { swc[wv] = cnt; swx[wv] = mx; swn[wv] = mn; }
    __syncthreads();
    if (t == 0) {
        int c = swc[0] + swc[1] + swc[2] + swc[3];
        int x = max(max(swx[0], swx[1]), max(swx[2], swx[3]));
        int n = min(min(swn[0], swn[1]), min(swn[2], swn[3]));
        __hip_atomic_store(&cntArr[chunk], c, __ATOMIC_RELAXED,
                           __HIP_MEMORY_SCOPE_AGENT);
        __hip_atomic_store(&maxArr[chunk], x, __ATOMIC_RELAXED,
                           __HIP_MEMORY_SCOPE_AGENT);
        __hip_atomic_store(&minArr[chunk], n, __ATOMIC_RELAXED,
                           __HIP_MEMORY_SCOPE_AGENT);
        oldc = __hip_atomic_fetch_add(&counters[img], 1u, __ATOMIC_ACQ_REL,
                                      __HIP_MEMORY_SCOPE_AGENT);
    }
    __syncthreads();
    if (oldc != CPI - 1) return;         // not this image's last finisher

    // ---- tail phase: this block is its image's 64th finisher ---------------
    int c0 = (t < CPI) ? __hip_atomic_load(&cntArr[img * CPI + t],
                  __ATOMIC_ACQUIRE, __HIP_MEMORY_SCOPE_AGENT) : 0;
    sc[t] = c0;
    sm[t] = (t < CPI) ? __hip_atomic_load(&maxArr[img * CPI + t],
                  __ATOMIC_ACQUIRE, __HIP_MEMORY_SCOPE_AGENT) : -1;
    sn[t] = (t < CPI) ? __hip_atomic_load(&minArr[img * CPI + t],
                  __ATOMIC_ACQUIRE, __HIP_MEMORY_SCOPE_AGENT) : HW;
    if (t == 0) result = -2;
    __syncthreads();
    for (int off = 1; off < 256; off <<= 1) {    // inclusive scan of counts
        int v2 = (t >= off) ? sc[t - off] : 0;
        __syncthreads();
        sc[t] += v2;
        __syncthreads();
    }
    int num = sc[255];
    int inc = sc[t], exc = inc - c0;
    for (int s = 128; s > 0; s >>= 1) {
        if (t < s) { sm[t] = max(sm[t], sm[t + s]); sn[t] = min(sn[t], sn[t + s]); }
        __syncthreads();
    }
    int last_root = sm[0], minFg = sn[0];
    int v;
    if (last_root >= 1) v = last_root;
    else if (last_root == 0) v = (minFg < HW) ? minFg : 1;
    else v = 1;
    if (v >= 1 && v <= num) {            // block-uniform branch
        if (exc < v && v <= inc) { sel_chunk = t; sel_base = exc; }
        __syncthreads();
        int c = sel_chunk, base = sel_base;
        int bL = c * 4096;
        int f[16];
        int sum = 0;
#pragma unroll
        for (int j = 0; j < 4; j++) {
            int off = bL + t * 16 + j * 4;
            int4 l4 = *(const int4*)(Li + off);
            const int* lp = (const int*)&l4;
#pragma unroll
            for (int k = 0; k < 4; k++) {
                f[j * 4 + k] = (lp[k] == off + k) ? 1 : 0;
                sum += f[j * 4 + k];
            }
        }
        __syncthreads();
        sc[t] = sum;
        __syncthreads();
        for (int off = 1; off < 256; off <<= 1) {
            int v2 = (t >= off) ? sc[t - off] : 0;
            __syncthreads();
            sc[t] += v2;
            __syncthreads();
        }
        int exc2 = sc[t] - sum;
        int need = v - base;
        if (exc2 < need && need <= sc[t]) {
            int run = exc2;
#pragma unroll
            for (int k = 0; k < 16; k++) {
                run += f[k];
                if (run == need) { result = bL + t * 16 + k; break; }
            }
        }
        __syncthreads();
    } else {
        __syncthreads();
    }
    int rvv = result;
    float blocksum = 0.0f;
    if (rvv >= 0) {                      // rare path: scan whole image
        const float* pi = pred + ((size_t)img << LOGHW);
        float acc = 0.0f;
        for (int it = 0; it < HW / 1024; it++) {
            int off = it * 1024 + t * 4;
            float4 p4 = *(const float4*)(pi + off);
            int4 l4 = *(const int4*)(Li + off);
            const float* pp = (const float*)&p4;
            const int* lp = (const int*)&l4;
#pragma unroll
            for (int k = 0; k < 4; k++) {
                int p = lp[k];
                if (p < 0) continue;
                int x = p, q = Li[x];
                while (q != x) { x = q; q = Li[x]; }
                if (x == rvv) {
                    float pr = pp[k];
                    acc += fmaxf(__logf(pr), -100.0f)
                         - fmaxf(__logf(1.0f - pr), -100.0f);
                }
            }
        }
        sf[t] = acc;
        __syncthreads();
        for (int s = 128; s > 0; s >>= 1) {
            if (t < s) sf[t] += sf[t + s];
            __syncthreads();
        }
        blocksum = sf[0];
    }
    if (t == 0) {
        __hip_atomic_store(&corr[img], blocksum, __ATOMIC_RELAXED,
                           __HIP_MEMORY_SCOPE_AGENT);
        oldg = __hip_atomic_fetch_add(&counters[NIMG], 1u, __ATOMIC_ACQ_REL,
                                      __HIP_MEMORY_SCOPE_AGENT);
    }
    __syncthreads();
    if (oldg != NIMG - 1) return;
    // ---- last of 32 images: final reduce -----------------------------------
    double acc = 0.0;
#pragma unroll
    for (int j = 0; j < 8; j++) acc += (double)partials[t + j * 256];
    if (t < NIMG)
        acc += (double)__hip_atomic_load(&corr[t], __ATOMIC_ACQUIRE,
                                         __HIP_MEMORY_SCOPE_AGENT);
    sd[t] = acc;
    __syncthreads();
    for (int s = 128; s > 0; s >>= 1) {
        if (t < s) sd[t] += sd[t + s];
        __syncthreads();
    }
    if (t == 0) out[0] = (float)(-sd[0] / (double)NTOT);
}

extern "C" void kernel_launch(void* const* d_in, const int* in_sizes, int n_in,
                              void* d_out, int out_size, void* d_ws, size_t ws_size,
                              hipStream_t stream) {
    const float* pred = (const float*)d_in[0];
    float* out = (float*)d_out;

    char* ws = (char*)d_ws;
    int* L = (int*)ws;                                        // 33.5 MB
    int* edges = (int*)(ws + (size_t)NTOT * 4);               // 2 MB (4 dirs)
    int* cntArr = edges + 4 * EDGE_N;                         // 8 KB
    int* maxArr = cntArr + NSCHUNK;                           // 8 KB
    int* minArr = maxArr + NSCHUNK;                           // 8 KB
    float* partials = (float*)(minArr + NSCHUNK);             // 8 KB
    float* corr = partials + NTILE;                           // 128 B
    unsigned int* counters = (unsigned int*)(corr + NIMG);    // 33 slots

    k_local<<<dim3(NTILE), dim3(512), 0, stream>>>(pred, L, partials, edges,
                                                   counters);
    k_border<<<dim3(NPAIR * 64 / 256), dim3(256), 0, stream>>>(edges, L);
    k_stats_tail<<<dim3(NSCHUNK), dim3(256), 0, stream>>>(L, pred, cntArr, maxArr,
                                                          minArr, partials, corr,
                                                          counters, out);
}

// Round 16
// 119.795 us; speedup vs baseline: 1.3808x; 1.3808x over previous
//
#include <hip/hip_runtime.h>
#include <math.h>

// Problem constants (fixed by reference setup_inputs): pred [32,1,512,512] f32
#define IMG_W 512
#define IMG_H 512
#define HW (IMG_W * IMG_H)      // 262144 = 2^18
#define LOGHW 18
#define NIMG 32
#define NTOT (NIMG * HW)        // 8388608
#define TILE 64
#define TPI 64                  // 8x8 tiles of 64x64 per image
#define NTILE (NIMG * TPI)      // 2048
#define CPI 64                  // stat-chunks per image (4096 px each)
#define NSCHUNK (NIMG * CPI)    // 2048
#define EDGE_N (NTILE * 64)     // 131072 entries per edge direction
#define NPAIR (NIMG * 112)      // 56 vertical + 56 horizontal tile-pairs/img
// NOTE (R6/R15 lesson): NO cross-block handshakes inside large grids. R6:
// 2048-way single counter = 56us serialization. R15: per-image 64-way acq_rel
// inside the 2048-block stats grid = 60us of L2 wbl2/inv thrash (gfx950
// agent-scope release/acquire writes back / invalidates L2; XCDs are not
// coherent). Separate tiny launches (~4us) always win. 32-way in a 32-block
// grid (k_tail) is the only safe pattern.
// NOTE (R12 lesson): no big register prefetch in k_local — VGPR 16->44
// halved occupancy (66->37%) and cost +11us. Occupancy > manual prefetch.
// NOTE (R8..R14): four structurally different k_local CCLs (per-px UF,
// run-start UF, mask UF, zero-barrier wave-per-tile) all land 120-121us
// total; k_local latency floor ~42-46us; harness fixed cost ~55us in-window.

// ---------------- lock-free min-index union-find ----------------------------
__device__ __forceinline__ void uf_unite(int* L, int a, int b) {
    while (true) {
        // find roots (reads may be stale -> only costs retries, never wrong)
        int p = ((volatile int*)L)[a];
        while (p != a) { a = p; p = ((volatile int*)L)[a]; }
        p = ((volatile int*)L)[b];
        while (p != b) { b = p; p = ((volatile int*)L)[b]; }
        if (a == b) return;
        if (a < b) { int t = a; a = b; b = t; }  // a > b
        int old = atomicMin(&L[a], b);
        if (old == a) return;
        a = old;
    }
}

// ---------------- K1: CCL + base BCE + edge export (R8/R13: measured best) --
// One block (512 thr, 8 waves) per 64x64 tile; row width == wave width.
// Pass 1: row-run labels via ballot (run start = min index of run) + fused
//   base BCE sum(fmax(log(1-p),-100)) with native __logf.
// Pass 2: vertical unites only at contact-run starts (~750/tile).
// Pass 3a: only run-starts chase to root (full compress).
// Pass 3b: every px root = lab[lab[px]] (2 LDS reads); write global L;
//   export the 4 tile-edge label vectors coalesced for k_border.
__global__ __launch_bounds__(512) void k_local(const float* __restrict__ pred,
                                               int* __restrict__ L,
                                               float* __restrict__ partials,
                                               int* __restrict__ edges,
                                               unsigned int* __restrict__ counter) {
    __shared__ int lab[TILE * TILE];   // 16 KB
    __shared__ float sred[512];        // 2 KB
    int tile = blockIdx.x;
    int img = tile >> 6;
    int t = tile & (TPI - 1);
    int ty = t >> 3, tx = t & 7;
    int baseLocal = (ty * TILE) * IMG_W + tx * TILE;  // image-local origin
    const float* pi = pred + ((size_t)img << LOGHW);
    int* Li = L + ((size_t)img << LOGHW);
    int tid = threadIdx.x;
    int lane = tid & 63, wave = tid >> 6;             // wave 0..7

    float acc = 0.0f;
    // ---- pass 1: row-run labels via ballot (wave w handles rows r%8==w) ----
#pragma unroll
    for (int j = 0; j < 8; j++) {
        int row = wave + j * 8;
        float p = pi[baseLocal + row * IMG_W + lane];
        acc += fmaxf(__logf(1.0f - p), -100.0f);   // 1-p exact for p>=0.5
        bool fg = (p >= 0.5f);
        unsigned long long bal = __ballot(fg);
        unsigned long long starts = bal & ~(bal << 1);
        unsigned long long maskle =
            (lane == 63) ? ~0ULL : ((1ULL << (lane + 1)) - 1ULL);
        int lb = -1;
        if (fg) {
            unsigned long long pre = starts & maskle;   // nonzero when fg
            lb = row * TILE + (63 - __builtin_clzll(pre));
        }
        lab[row * TILE + lane] = lb;
    }
    __syncthreads();
    // ---- pass 2: vertical unites, one per contact-run ----------------------
#pragma unroll
    for (int j = 0; j < 8; j++) {
        int row = wave + j * 8;
        if (row == 0) continue;                   // wave-uniform
        int i = row * TILE + lane;
        bool c = (lab[i] >= 0) && (lab[i - TILE] >= 0);
        unsigned long long cb = __ballot(c);
        unsigned long long cs = cb & ~(cb << 1);  // first lane of each contact
        if ((cs >> lane) & 1ULL) uf_unite(lab, i, i - TILE);
    }
    __syncthreads();
    // ---- pass 3a: run-starts chase to root (path halving + full compress) --
#pragma unroll
    for (int j = 0; j < 8; j++) {
        int row = wave + j * 8;
        int i = row * TILE + lane;
        bool fg = (lab[i] >= 0);
        unsigned long long bal = __ballot(fg);
        unsigned long long st = bal & ~(bal << 1);
        if ((st >> lane) & 1ULL) {
            int x = i, p = lab[x];
            while (p != x) {
                int g = lab[p];
                lab[x] = g;          // halving: benign race, ancestors only
                x = g;
                p = lab[x];
            }
            lab[i] = x;              // full compress for the start entry
        }
    }
    __syncthreads();
    // ---- pass 3b: gather roots (2 LDS reads/px) + global write (int4) ------
#pragma unroll
    for (int j = 0; j < 2; j++) {
        int i4 = (tid + j * 512) * 4;
        int ly = i4 >> 6, lx = i4 & 63;
        int4 o;
        int* op = (int*)&o;
#pragma unroll
        for (int k = 0; k < 4; k++) {
            int s = lab[i4 + k];                 // runstart (or root if start)
            if (s < 0) op[k] = -1;
            else {
                int r = lab[s];                  // root (starts compressed)
                op[k] = baseLocal + (r >> 6) * IMG_W + (r & 63);
            }
        }
        *(int4*)(Li + baseLocal + ly * IMG_W + lx) = o;
    }
    // ---- edge export: 4 x 64 labels, coalesced -----------------------------
    if (tid < 256) {
        int e = tid >> 6;                        // 0=T,1=B,2=L,3=R
        int q = tid & 63;
        int px = (e == 0) ? q
               : (e == 1) ? (63 * TILE + q)
               : (e == 2) ? (q * TILE)
               :            (q * TILE + 63);
        int s = lab[px];
        int val = -1;
        if (s >= 0) {
            int r = lab[s];
            val = baseLocal + (r >> 6) * IMG_W + (r & 63);
        }
        edges[e * EDGE_N + tile * 64 + q] = val;
    }
    // ---- base BCE block reduce ---------------------------------------------
    sred[tid] = acc;
    __syncthreads();
    for (int s = 256; s > 0; s >>= 1) {
        if (tid < s) sred[tid] += sred[tid + s];
        __syncthreads();
    }
    if (tid == 0) partials[blockIdx.x] = sred[0];
    if (blockIdx.x == 0 && tid == 0) *counter = 0u;   // ws is 0xAA-poisoned
}

// ---------------- K2: cross-tile border unites from compact edges -----------
__global__ __launch_bounds__(256) void k_border(const int* __restrict__ edges,
                                                int* __restrict__ L) {
    int gid = blockIdx.x * blockDim.x + threadIdx.x;
    int pair = gid >> 6;                 // wave-uniform
    int lane = gid & 63;
    int a, b, img;
    if (pair < NIMG * 56) {              // vertical: (ty,tx)-(ty,tx+1)
        img = pair / 56;
        int w = pair - img * 56;
        int ty = w / 7, tx = w - ty * 7;
        int tl = img * TPI + ty * 8 + tx;
        a = edges[3 * EDGE_N + tl * 64 + lane];        // right edge of left
        b = edges[2 * EDGE_N + (tl + 1) * 64 + lane];  // left edge of right
    } else {                             // horizontal: (ty,tx)-(ty+1,tx)
        int p2 = pair - NIMG * 56;
        img = p2 / 56;
        int w = p2 - img * 56;
        int ty = w >> 3, tx = w & 7;
        int tu = img * TPI + ty * 8 + tx;
        a = edges[1 * EDGE_N + tu * 64 + lane];        // bottom edge of upper
        b = edges[0 * EDGE_N + (tu + 8) * 64 + lane];  // top edge of lower
    }
    bool c = (a >= 0) && (b >= 0);
    unsigned long long cb = __ballot(c);
    unsigned long long cs = cb & ~(cb << 1);           // contact-run starts
    if ((cs >> lane) & 1ULL)
        uf_unite(L + ((size_t)img << LOGHW), a, b);
}

// ---------------- K3: per-chunk stats (4096 px): roots, maxRoot, minFg ------
// Root flags (L[i]==i) are invariant under path compression: no chase needed.
__global__ __launch_bounds__(256) void k_stats(const int* __restrict__ L,
                                               int* __restrict__ cntArr,
                                               int* __restrict__ maxArr,
                                               int* __restrict__ minArr) {
    __shared__ int s1[256], s2[256], s3[256];
    int chunk = blockIdx.x;
    int img = chunk >> 6;
    int baseL = (chunk & 63) * 4096;             // image-local
    const int* Li = L + ((size_t)img << LOGHW);
    int t = threadIdx.x;
    int cnt = 0, mx = -1, mn = HW;
#pragma unroll
    for (int j = 0; j < 4; j++) {
        int off = baseL + (t + j * 256) * 4;
        int4 l4 = *(const int4*)(Li + off);
        const int* lp = (const int*)&l4;
#pragma unroll
        for (int k = 0; k < 4; k++) {
            int local = off + k;
            int p = lp[k];
            bool root = (p == local);
            cnt += root ? 1 : 0;
            if (root && local > mx) mx = local;
            if (p >= 0 && local >= 1 && local < mn) mn = local;
        }
    }
    s1[t] = cnt; s2[t] = mx; s3[t] = mn;
    __syncthreads();
    for (int s = 128; s > 0; s >>= 1) {
        if (t < s) {
            s1[t] += s1[t + s];
            s2[t] = max(s2[t], s2[t + s]);
            s3[t] = min(s3[t], s3[t + s]);
        }
        __syncthreads();
    }
    if (t == 0) { cntArr[chunk] = s1[0]; maxArr[chunk] = s2[0]; minArr[chunk] = s3[0]; }
}

// ---------------- K4: fused rv + correction + final reduce ------------------
// One block per image. v = argmax(lf[1:]) + 1 equals: index of LAST root
// (if >=1); else (single component rooted at 0) first fg index >=1, or 1 if
// none; else 1. rv = v-th root in raster order if 1<=v<=num, else -2.
// If rv >= 0 (rare), this block scans its image for the correction term
// sum_{root==rv}(logp - log1mp). Last of the 32 blocks (32-way counter in a
// 32-block grid — the only safe handshake pattern) reduces k_local's 2048
// base partials + 32 corrections.
__global__ __launch_bounds__(256) void k_tail(const int* __restrict__ cntArr,
                                              const int* __restrict__ maxArr,
                                              const int* __restrict__ minArr,
                                              const int* __restrict__ L,
                                              const float* __restrict__ pred,
                                              const float* __restrict__ partials,
                                              float* __restrict__ corr,
                                              unsigned int* __restrict__ counter,
                                              float* __restrict__ out) {
    __shared__ int sc[256], sm[256], sn[256];
    __shared__ int sel_chunk, sel_base, result;
    __shared__ float sf[256];
    __shared__ double sd[256];
    __shared__ unsigned int oldc;
    int img = blockIdx.x, t = threadIdx.x;
    const int* Li = L + ((size_t)img << LOGHW);
    int cnt = (t < CPI) ? cntArr[img * CPI + t] : 0;
    sc[t] = cnt;
    sm[t] = (t < CPI) ? maxArr[img * CPI + t] : -1;
    sn[t] = (t < CPI) ? minArr[img * CPI + t] : HW;
    if (t == 0) result = -2;
    __syncthreads();
    for (int off = 1; off < 256; off <<= 1) {    // inclusive scan of counts
        int v2 = (t >= off) ? sc[t - off] : 0;
        __syncthreads();
        sc[t] += v2;
        __syncthreads();
    }
    int num = sc[255];
    int inc = sc[t], exc = inc - cnt;
    for (int s = 128; s > 0; s >>= 1) {
        if (t < s) { sm[t] = max(sm[t], sm[t + s]); sn[t] = min(sn[t], sn[t + s]); }
        __syncthreads();
    }
    int last_root = sm[0], minFg = sn[0];
    int v;
    if (last_root >= 1) v = last_root;
    else if (last_root == 0) v = (minFg < HW) ? minFg : 1;
    else v = 1;
    if (v >= 1 && v <= num) {            // block-uniform branch
        if (exc < v && v <= inc) { sel_chunk = t; sel_base = exc; }
        __syncthreads();
        int c = sel_chunk, base = sel_base;
        int baseL = c * 4096;
        int f[16];
        int sum = 0;
#pragma unroll
        for (int j = 0; j < 4; j++) {
            int off = baseL + t * 16 + j * 4;
            int4 l4 = *(const int4*)(Li + off);
            const int* lp = (const int*)&l4;
#pragma unroll
            for (int k = 0; k < 4; k++) {
                f[j * 4 + k] = (lp[k] == off + k) ? 1 : 0;
                sum += f[j * 4 + k];
            }
        }
        __syncthreads();
        sc[t] = sum;
        __syncthreads();
        for (int off = 1; off < 256; off <<= 1) {
            int v2 = (t >= off) ? sc[t - off] : 0;
            __syncthreads();
            sc[t] += v2;
            __syncthreads();
        }
        int exc2 = sc[t] - sum;
        int need = v - base;
        if (exc2 < need && need <= sc[t]) {
            int run = exc2;
#pragma unroll
            for (int k = 0; k < 16; k++) {
                run += f[k];
                if (run == need) { result = baseL + t * 16 + k; break; }
            }
        }
        __syncthreads();
    } else {
        __syncthreads();
    }
    int rvv = result;
    float blocksum = 0.0f;
    if (rvv >= 0) {                      // rare path: scan whole image
        const float* pi = pred + ((size_t)img << LOGHW);
        float acc = 0.0f;
        for (int it = 0; it < HW / 1024; it++) {
            int off = it * 1024 + t * 4;
            float4 p4 = *(const float4*)(pi + off);
            int4 l4 = *(const int4*)(Li + off);
            const float* pp = (const float*)&p4;
            const int* lp = (const int*)&l4;
#pragma unroll
            for (int k = 0; k < 4; k++) {
                int p = lp[k];
                if (p < 0) continue;
                int x = p, q = Li[x];
                while (q != x) { x = q; q = Li[x]; }
                if (x == rvv) {
                    float pr = pp[k];
                    acc += fmaxf(__logf(pr), -100.0f)
                         - fmaxf(__logf(1.0f - pr), -100.0f);
                }
            }
        }
        sf[t] = acc;
        __syncthreads();
        for (int s = 128; s > 0; s >>= 1) {
            if (t < s) sf[t] += sf[t + s];
            __syncthreads();
        }
        blocksum = sf[0];
    }
    if (t == 0) {
        __hip_atomic_store(&corr[img], blocksum, __ATOMIC_RELAXED,
                           __HIP_MEMORY_SCOPE_AGENT);
        oldc = __hip_atomic_fetch_add(counter, 1u, __ATOMIC_ACQ_REL,
                                      __HIP_MEMORY_SCOPE_AGENT);
    }
    __syncthreads();
    if (oldc != NIMG - 1) return;
    // ---- last of 32 blocks: final reduce -----------------------------------
    double acc = 0.0;
#pragma unroll
    for (int j = 0; j < 8; j++) acc += (double)partials[t + j * 256];
    if (t < NIMG)
        acc += (double)__hip_atomic_load(&corr[t], __ATOMIC_ACQUIRE,
                                         __HIP_MEMORY_SCOPE_AGENT);
    sd[t] = acc;
    __syncthreads();
    for (int s = 128; s > 0; s >>= 1) {
        if (t < s) sd[t] += sd[t + s];
        __syncthreads();
    }
    if (t == 0) out[0] = (float)(-sd[0] / (double)NTOT);
}

extern "C" void kernel_launch(void* const* d_in, const int* in_sizes, int n_in,
                              void* d_out, int out_size, void* d_ws, size_t ws_size,
                              hipStream_t stream) {
    const float* pred = (const float*)d_in[0];
    float* out = (float*)d_out;

    char* ws = (char*)d_ws;
    int* L = (int*)ws;                                        // 33.5 MB
    int* edges = (int*)(ws + (size_t)NTOT * 4);               // 2 MB (4 dirs)
    int* cntArr = edges + 4 * EDGE_N;                         // 8 KB
    int* maxArr = cntArr + NSCHUNK;                           // 8 KB
    int* minArr = maxArr + NSCHUNK;                           // 8 KB
    float* partials = (float*)(minArr + NSCHUNK);             // 8 KB
    float* corr = partials + NTILE;                           // 128 B
    unsigned int* counter = (unsigned int*)(corr + NIMG);     // 4 B

    k_local<<<dim3(NTILE), dim3(512), 0, stream>>>(pred, L, partials, edges, counter);
    k_border<<<dim3(NPAIR * 64 / 256), dim3(256), 0, stream>>>(edges, L);
    k_stats<<<dim3(NSCHUNK), dim3(256), 0, stream>>>(L, cntArr, maxArr, minArr);
    k_tail<<<dim3(NIMG), dim3(256), 0, stream>>>(cntArr, maxArr, minArr, L, pred,
                                                 partials, corr, counter, out);
}